// Round 1
// baseline (61.290 us; speedup 1.0000x reference)
//
#include <hip/hip_runtime.h>
#include <stdint.h>

// DKD keypoint detect + describe, MI355X.
// H=W=1536, C=64, KERNEL=4 -> 384x384 = 147456 tiles, top-500 by (value, idx).

#define HH 1536
#define WW 1536
#define CC 64
#define KER 4
#define TH (HH / KER)          // 384
#define TW (WW / KER)          // 384
#define NTILES (TH * TW)       // 147456
#define TOPK 500
#define CAP 2048

// ws layout (bytes):
//   keys  : [0, NTILES*8)                          = 1,179,648
//   hist1 : 4096 u32 @ ZOFF
//   hist2 : 4096 u32
//   hist3 : 256 u32
//   counter: 1 u32            (hist1..counter contiguous -> one memset)
//   buf   : CAP u64 @ BUF_OFF (8-aligned)
//   sel   : TOPK i32 @ SEL_OFF
#define ZOFF   ((size_t)NTILES * 8)
#define ZBYTES ((4096 + 4096 + 256 + 1) * 4)
#define BUF_OFF (ZOFF + 33808)            // 8-aligned pad after zero region
#define SEL_OFF (BUF_OFF + (size_t)CAP * 8)

typedef unsigned long long u64;
typedef unsigned int u32;

// ---------------- kernel A: tile max/argmax -> keys, level-1 histogram -----
__global__ __launch_bounds__(256) void kA(const float* __restrict__ s,
                                          u64* __restrict__ keys,
                                          u32* __restrict__ hist1) {
    __shared__ u32 lh[4096];
    for (int i = threadIdx.x; i < 4096; i += 256) lh[i] = 0;
    __syncthreads();

    int t = blockIdx.x * 256 + threadIdx.x;      // exact cover: 576*256 = NTILES
    int tr = t / TW, tc = t % TW;
    int r0 = tr * KER, c0 = tc * KER;
    float best = -1.0f;
    int arg = 0;
#pragma unroll
    for (int dr = 0; dr < 4; ++dr) {
        int r = r0 + dr;
        float4 q = *reinterpret_cast<const float4*>(s + (size_t)r * WW + c0);
        bool rz = (r < 3) | (r >= HH - 2);
        float e0 = q.x, e1 = q.y, e2 = q.z, e3 = q.w;
        float ee[4] = {e0, e1, e2, e3};
#pragma unroll
        for (int dc = 0; dc < 4; ++dc) {
            int c = c0 + dc;
            float v = (rz | (c < 3) | (c >= WW - 2)) ? 0.0f : ee[dc];
            if (v > best) { best = v; arg = dr * 4 + dc; }   // first-max (jnp.argmax)
        }
    }
    u32 vb = __float_as_uint(best);              // scores in [0,1): bits monotone
    keys[t] = ((u64)vb << 32) | (u32)((t << 4) | arg);
    atomicAdd(&lh[min(vb >> 20, 4095u)], 1u);
    __syncthreads();
    for (int i = threadIdx.x; i < 4096; i += 256)
        if (lh[i]) atomicAdd(&hist1[i], lh[i]);
}

// -------- block-redundant level finder: largest bin with suffix-count >= K --
template <int NB>
__device__ void find_level(const u32* __restrict__ gh, int K, int& p_res, int& ab_res) {
    constexpr int PER = NB / 256;
    __shared__ u32 ssum[256];
    __shared__ int sp, sab;
    int t = threadIdx.x;
    u32 loc[PER];
    u32 s = 0;
#pragma unroll
    for (int i = 0; i < PER; ++i) { loc[i] = gh[t * PER + i]; s += loc[i]; }
    ssum[t] = s;
    __syncthreads();
    for (int off = 1; off < 256; off <<= 1) {     // inclusive suffix scan
        u32 v = (t + off < 256) ? ssum[t + off] : 0u;
        __syncthreads();
        ssum[t] += v;
        __syncthreads();
    }
    u32 suffIncl = ssum[t];
    u32 suffExcl = (t < 255) ? ssum[t + 1] : 0u;
    if (suffExcl < (u32)K && suffIncl >= (u32)K) {  // exactly one thread
        u32 run = suffExcl;
        for (int i = PER - 1; i >= 0; --i) {
            run += loc[i];
            if (run >= (u32)K) { sp = t * PER + i; sab = (int)(run - loc[i]); break; }
        }
    }
    __syncthreads();
    p_res = sp; ab_res = sab;
    __syncthreads();   // allow shared reuse by a subsequent call
}

// ---------------- level-2 histogram ----------------------------------------
__global__ __launch_bounds__(256) void kH2(const u64* __restrict__ keys,
                                           const u32* __restrict__ hist1,
                                           u32* __restrict__ hist2) {
    int p1, ab1;
    find_level<4096>(hist1, TOPK, p1, ab1);
    __shared__ u32 lh[4096];
    for (int i = threadIdx.x; i < 4096; i += 256) lh[i] = 0;
    __syncthreads();
    int t = blockIdx.x * 256 + threadIdx.x;
    u32 v = (u32)(keys[t] >> 32);
    if ((int)min(v >> 20, 4095u) == p1) atomicAdd(&lh[(v >> 8) & 0xFFF], 1u);
    __syncthreads();
    for (int i = threadIdx.x; i < 4096; i += 256)
        if (lh[i]) atomicAdd(&hist2[i], lh[i]);
}

// ---------------- level-3 histogram ----------------------------------------
__global__ __launch_bounds__(256) void kH3(const u64* __restrict__ keys,
                                           const u32* __restrict__ hist1,
                                           const u32* __restrict__ hist2,
                                           u32* __restrict__ hist3) {
    int p1, ab1, p2, ab2;
    find_level<4096>(hist1, TOPK, p1, ab1);
    int K1 = TOPK - ab1;
    find_level<4096>(hist2, K1, p2, ab2);
    u32 P2 = ((u32)p1 << 12) | (u32)p2;
    __shared__ u32 lh[256];
    if (threadIdx.x < 256) lh[threadIdx.x] = 0;
    __syncthreads();
    int t = blockIdx.x * 256 + threadIdx.x;
    u32 v = (u32)(keys[t] >> 32);
    if ((v >> 8) == P2) atomicAdd(&lh[v & 0xFF], 1u);
    __syncthreads();
    if (lh[threadIdx.x]) atomicAdd(&hist3[threadIdx.x], lh[threadIdx.x]);
}

// ---------------- compact survivors (v >= v*) ------------------------------
__global__ __launch_bounds__(256) void kC(const u64* __restrict__ keys,
                                          const u32* __restrict__ hist1,
                                          const u32* __restrict__ hist2,
                                          const u32* __restrict__ hist3,
                                          u32* __restrict__ counter,
                                          u64* __restrict__ buf) {
    int p1, ab1, p2, ab2, p3, ab3;
    find_level<4096>(hist1, TOPK, p1, ab1);
    int K1 = TOPK - ab1;
    find_level<4096>(hist2, K1, p2, ab2);
    int K2 = K1 - ab2;
    find_level<256>(hist3, K2, p3, ab3);
    u32 vstar = (((u32)p1 << 12 | (u32)p2) << 8) | (u32)p3;
    int t = blockIdx.x * 256 + threadIdx.x;
    u64 k = keys[t];
    u32 v = (u32)(k >> 32);
    if (v >= vstar) {
        u32 pos = atomicAdd(counter, 1u);
        if (pos < CAP) buf[pos] = k;
    }
}

// ------------- rank survivors, emit keypoints + scores + sel ---------------
__global__ __launch_bounds__(1024) void kR(const u64* __restrict__ buf,
                                           const u32* __restrict__ counter,
                                           float* __restrict__ out,
                                           int* __restrict__ sel) {
    __shared__ u64 sk[CAP];
    int M = (int)*counter;
    if (M > CAP) M = CAP;
    for (int i = threadIdx.x; i < M; i += 1024) sk[i] = buf[i];
    __syncthreads();
    int start = M - TOPK;
    if (start < 0) start = 0;
    for (int e = threadIdx.x; e < M; e += 1024) {
        u64 k = sk[e];
        int rank = 0;
        for (int j = 0; j < M; ++j) rank += (sk[j] < k);  // keys distinct
        if (rank >= start) {
            int jout = rank - start;                       // ascending output
            if (jout < TOPK) {
                u32 low = (u32)(k & 0xFFFFFFFFu);
                int tt = (int)(low >> 4), arg = (int)(low & 15u);
                int gr = (tt / TW) * KER + (arg >> 2);
                int gc = (tt % TW) * KER + (arg & 3);
                out[jout * 2 + 0] = (float)gc;             // x
                out[jout * 2 + 1] = (float)gr;             // y
                out[TOPK * 2 + TOPK * CC + jout] = __uint_as_float((u32)(k >> 32));
                sel[jout] = (gr << 16) | gc;
            }
        }
    }
}

// ------------- descriptor gather + L2 normalize: 1 wave / keypoint ---------
__global__ __launch_bounds__(512) void kG(const float* __restrict__ dmap,
                                          const int* __restrict__ sel,
                                          float* __restrict__ out) {
    int w = blockIdx.x * 8 + (threadIdx.x >> 6);
    if (w >= TOPK) return;                     // whole wave uniform
    int lane = threadIdx.x & 63;
    int yx = sel[w];
    int y = yx >> 16, x = yx & 0xFFFF;
    float v = dmap[(size_t)lane * (HH * WW) + (size_t)y * WW + x];
    float ss = v * v;
#pragma unroll
    for (int off = 32; off; off >>= 1) ss += __shfl_xor(ss, off);
    float inv = 1.0f / sqrtf(ss);
    out[TOPK * 2 + w * CC + lane] = v * inv;
}

extern "C" void kernel_launch(void* const* d_in, const int* in_sizes, int n_in,
                              void* d_out, int out_size, void* d_ws, size_t ws_size,
                              hipStream_t stream) {
    const float* scores = (const float*)d_in[0];   // [1,1,1536,1536] f32
    const float* dmap   = (const float*)d_in[1];   // [1,64,1536,1536] f32
    float* out = (float*)d_out;                    // 1000 + 32000 + 500 = 33500 f32
    char* ws = (char*)d_ws;

    u64* keys  = (u64*)ws;
    u32* hist1 = (u32*)(ws + ZOFF);
    u32* hist2 = hist1 + 4096;
    u32* hist3 = hist2 + 4096;
    u32* counter = hist3 + 256;
    u64* buf = (u64*)(ws + BUF_OFF);
    int* sel = (int*)(ws + SEL_OFF);

    hipMemsetAsync(hist1, 0, ZBYTES, stream);      // re-zero every call

    kA <<<NTILES / 256, 256, 0, stream>>>(scores, keys, hist1);
    kH2<<<NTILES / 256, 256, 0, stream>>>(keys, hist1, hist2);
    kH3<<<NTILES / 256, 256, 0, stream>>>(keys, hist1, hist2, hist3);
    kC <<<NTILES / 256, 256, 0, stream>>>(keys, hist1, hist2, hist3, counter, buf);
    kR <<<1, 1024, 0, stream>>>(buf, counter, out, sel);
    kG <<<(TOPK * CC + 511) / 512, 512, 0, stream>>>(dmap, sel, out);
}

// Round 2
// 42.162 us; speedup vs baseline: 1.4537x; 1.4537x over previous
//
#include <hip/hip_runtime.h>
#include <stdint.h>

// DKD keypoint detect + describe, MI355X — 4-dispatch pipeline.
// H=W=1536, C=64, KERNEL=4 -> 384x384 = 147456 tiles, top-500 by (value, idx).

#define HH 1536
#define WW 1536
#define CC 64
#define KER 4
#define TH (HH / KER)          // 384
#define TW (WW / KER)          // 384
#define NTILES (TH * TW)       // 147456
#define TOPK 500
#define CAP 2048

// ws layout (bytes):
//   keys   : [0, NTILES*8)               = 1,179,648
//   hist   : 4096 u32 @ ZOFF
//   counter: 1 u32  (contiguous with hist -> one memset of ZBYTES)
//   buf    : CAP u64 @ BUF_OFF (8-aligned)
#define ZOFF    ((size_t)NTILES * 8)
#define ZBYTES  ((4096 + 1) * 4)
#define BUF_OFF (ZOFF + 16392)

typedef unsigned long long u64;
typedef unsigned int u32;

// Monotone 4096-bin map for v in [0,1): bits [22:11] of mantissa when exp==126
// (v in [0.5,1)); everything below 0.5+2^-12 folds into bin 0 (never top-500).
__device__ __forceinline__ int vbin(u32 b) {
    return (b < 0x3F000000u) ? 0 : (int)((b - 0x3F000000u) >> 11);
}

// ---------------- kernel A: tile max/argmax -> keys + histogram ------------
__global__ __launch_bounds__(256) void kA(const float* __restrict__ s,
                                          u64* __restrict__ keys,
                                          u32* __restrict__ hist) {
    __shared__ u32 lh[4096];
    for (int i = threadIdx.x; i < 4096; i += 256) lh[i] = 0;
    __syncthreads();

    int t = blockIdx.x * 256 + threadIdx.x;      // exact cover: 576*256 = NTILES
    int tr = t / TW, tc = t % TW;
    int r0 = tr * KER, c0 = tc * KER;
    float best = -1.0f;
    int arg = 0;
#pragma unroll
    for (int dr = 0; dr < 4; ++dr) {
        int r = r0 + dr;
        float4 q = *reinterpret_cast<const float4*>(s + (size_t)r * WW + c0);
        bool rz = (r < 3) | (r >= HH - 2);
        float ee[4] = {q.x, q.y, q.z, q.w};
#pragma unroll
        for (int dc = 0; dc < 4; ++dc) {
            int c = c0 + dc;
            float v = (rz | (c < 3) | (c >= WW - 2)) ? 0.0f : ee[dc];
            if (v > best) { best = v; arg = dr * 4 + dc; }   // first-max (jnp.argmax)
        }
    }
    u32 vb = __float_as_uint(best);              // scores in [0,1): bits monotone
    keys[t] = ((u64)vb << 32) | (u32)((t << 4) | arg);
    atomicAdd(&lh[vbin(vb)], 1u);
    __syncthreads();
    for (int i = threadIdx.x; i < 4096; i += 256)
        if (lh[i]) atomicAdd(&hist[i], lh[i]);
}

// -------- block-redundant level finder: largest bin with suffix-count >= K --
template <int NB>
__device__ void find_level(const u32* __restrict__ gh, int K, int& p_res, int& ab_res) {
    constexpr int PER = NB / 256;
    __shared__ u32 ssum[256];
    __shared__ int sp, sab;
    int t = threadIdx.x;
    u32 loc[PER];
    u32 s = 0;
#pragma unroll
    for (int i = 0; i < PER; ++i) { loc[i] = gh[t * PER + i]; s += loc[i]; }
    ssum[t] = s;
    __syncthreads();
    for (int off = 1; off < 256; off <<= 1) {     // inclusive suffix scan
        u32 v = (t + off < 256) ? ssum[t + off] : 0u;
        __syncthreads();
        ssum[t] += v;
        __syncthreads();
    }
    u32 suffIncl = ssum[t];
    u32 suffExcl = (t < 255) ? ssum[t + 1] : 0u;
    if (suffExcl < (u32)K && suffIncl >= (u32)K) {  // exactly one thread
        u32 run = suffExcl;
        for (int i = PER - 1; i >= 0; --i) {
            run += loc[i];
            if (run >= (u32)K) { sp = t * PER + i; sab = (int)(run - loc[i]); break; }
        }
    }
    __syncthreads();
    p_res = sp; ab_res = sab;
}

// ---------------- threshold + compact survivors (v >= v*) ------------------
__global__ __launch_bounds__(256) void kC(const u64* __restrict__ keys,
                                          const u32* __restrict__ hist,
                                          u32* __restrict__ counter,
                                          u64* __restrict__ buf) {
    int p, ab;
    find_level<4096>(hist, TOPK, p, ab);
    u32 vstar = p ? (0x3F000000u + ((u32)p << 11)) : 0u;
    int base = blockIdx.x * 1024 + threadIdx.x;   // 144 blocks * 1024 = NTILES
#pragma unroll
    for (int kk = 0; kk < 4; ++kk) {
        u64 key = keys[base + kk * 256];
        if ((u32)(key >> 32) >= vstar) {
            u32 pos = atomicAdd(counter, 1u);
            if (pos < CAP) buf[pos] = key;
        }
    }
}

// --- rank survivors + emit keypoints/scores + gather/normalize descriptors --
// One wave per survivor slot: rank by lane-parallel count, then the winning
// wave gathers its descriptor (lane = channel) and L2-normalizes in-register.
__global__ __launch_bounds__(512) void kRG(const u64* __restrict__ buf,
                                           const u32* __restrict__ counter,
                                           const float* __restrict__ dmap,
                                           float* __restrict__ out) {
    __shared__ u64 sk[CAP];
    int M = (int)*counter;
    if (M > CAP) M = CAP;
    for (int i = threadIdx.x; i < M; i += 512) sk[i] = buf[i];
    __syncthreads();

    int g = blockIdx.x * 8 + (threadIdx.x >> 6);   // global wave id = survivor idx
    if (g >= M) return;
    int lane = threadIdx.x & 63;
    u64 k = sk[g];
    int rank = 0;
    for (int j = lane; j < M; j += 64) rank += (sk[j] < k);   // keys distinct
#pragma unroll
    for (int off = 32; off; off >>= 1) rank += __shfl_xor(rank, off);

    int start = M - TOPK;
    if (start < 0) start = 0;
    if (rank < start) return;
    int jout = rank - start;                        // ascending output order
    if (jout >= TOPK) return;                       // safety

    u32 low = (u32)k;
    int tt = (int)(low >> 4), arg = (int)(low & 15u);
    int gr = (tt / TW) * KER + (arg >> 2);
    int gc = (tt % TW) * KER + (arg & 3);

    float v = dmap[(size_t)lane * (HH * WW) + (size_t)gr * WW + gc];
    float ss = v * v;
#pragma unroll
    for (int off = 32; off; off >>= 1) ss += __shfl_xor(ss, off);
    float inv = 1.0f / sqrtf(ss);
    out[TOPK * 2 + jout * CC + lane] = v * inv;

    if (lane == 0) {
        out[jout * 2 + 0] = (float)gc;              // x
        out[jout * 2 + 1] = (float)gr;              // y
        out[TOPK * 2 + TOPK * CC + jout] = __uint_as_float((u32)(k >> 32));
    }
}

extern "C" void kernel_launch(void* const* d_in, const int* in_sizes, int n_in,
                              void* d_out, int out_size, void* d_ws, size_t ws_size,
                              hipStream_t stream) {
    const float* scores = (const float*)d_in[0];   // [1,1,1536,1536] f32
    const float* dmap   = (const float*)d_in[1];   // [1,64,1536,1536] f32
    float* out = (float*)d_out;                    // 1000 + 32000 + 500 f32
    char* ws = (char*)d_ws;

    u64* keys    = (u64*)ws;
    u32* hist    = (u32*)(ws + ZOFF);
    u32* counter = hist + 4096;
    u64* buf     = (u64*)(ws + BUF_OFF);

    hipMemsetAsync(hist, 0, ZBYTES, stream);       // re-zero every call

    kA <<<NTILES / 256, 256, 0, stream>>>(scores, keys, hist);
    kC <<<NTILES / 1024, 256, 0, stream>>>(keys, hist, counter, buf);
    kRG<<<CAP / 8, 512, 0, stream>>>(buf, counter, dmap, out);
}